// Round 5
// baseline (293.227 us; speedup 1.0000x reference)
//
#include <hip/hip_runtime.h>
#include <stdint.h>

#define BATCH 16
#define CH    256
#define NSP   4096   // 64*64 spatial
#define NH    4
#define HD    64

typedef __attribute__((ext_vector_type(8))) short bf16x8;
typedef __attribute__((ext_vector_type(4))) float f32x4;
typedef __attribute__((ext_vector_type(4))) unsigned int u32x4;

__device__ __forceinline__ short f2bf(float f) {
    union { float f; unsigned u; } v; v.f = f;
    unsigned r = (v.u + 0x7fffu + ((v.u >> 16) & 1u)) >> 16;
    return (short)r;
}
__device__ __forceinline__ float bf2f(short s) {
    union { float f; unsigned u; } v; v.u = ((unsigned)(unsigned short)s) << 16;
    return v.f;
}

// ---------------- fused: GN stats + sc/sh tables (blocks 0..511) + weight convert (512..767) ----
__global__ __launch_bounds__(256) void k_pre(
        const float* __restrict__ x, const float* __restrict__ wq, const float* __restrict__ wo,
        const float* __restrict__ gamma, const float* __restrict__ beta,
        float* __restrict__ sc_tab, float* __restrict__ sh_tab,
        short* __restrict__ wq_bf, short* __restrict__ wo_bf) {
    int bg = blockIdx.x;
    if (bg < 512) {
        const float4* p = (const float4*)(x + (size_t)bg * 32768);
        float s = 0.f, sq = 0.f;
        #pragma unroll 4
        for (int i = threadIdx.x; i < 8192; i += 256) {
            float4 v = p[i];
            s  += v.x + v.y + v.z + v.w;
            sq += v.x * v.x + v.y * v.y + v.z * v.z + v.w * v.w;
        }
        for (int off = 32; off; off >>= 1) { s += __shfl_down(s, off); sq += __shfl_down(sq, off); }
        __shared__ float ls[4], lq[4];
        int w = threadIdx.x >> 6;
        if ((threadIdx.x & 63) == 0) { ls[w] = s; lq[w] = sq; }
        __syncthreads();
        if (threadIdx.x == 0) {
            float S = ls[0] + ls[1] + ls[2] + ls[3];
            float Q = lq[0] + lq[1] + lq[2] + lq[3];
            float m = S / 32768.f;
            float var = Q / 32768.f - m * m;
            ls[0] = m; lq[0] = rsqrtf(var + 1e-5f);
        }
        __syncthreads();
        if (threadIdx.x < 8) {
            int b = bg >> 5, g = bg & 31, c = g * 8 + threadIdx.x;
            float r = lq[0], mm = ls[0];
            float sc = r * gamma[c];
            sc_tab[b * 256 + c] = sc;
            sh_tab[b * 256 + c] = beta[c] - mm * sc;
        }
    } else {
        int idx = ((bg - 512) * 256 + threadIdx.x) * 4;
        float4 v;
        short* dst;
        if (idx < 196608) { v = *(const float4*)(wq + idx); dst = wq_bf + idx; }
        else              { v = *(const float4*)(wo + (idx - 196608)); dst = wo_bf + (idx - 196608); }
        unsigned p0 = ((unsigned)(unsigned short)f2bf(v.x)) | (((unsigned)(unsigned short)f2bf(v.y)) << 16);
        unsigned p1 = ((unsigned)(unsigned short)f2bf(v.z)) | (((unsigned)(unsigned short)f2bf(v.w)) << 16);
        uint2 pk; pk.x = p0; pk.y = p1;
        *(uint2*)dst = pk;
    }
}

// ---------------- fused GN-apply + QKV + kv^T/ksum partials + q_t ----------------
// 512 threads / 8 waves per block, SAME per-block work as the 90us R0 version.
// Mechanism: TLP. 8-wave blocks double resident waves/CU (16 vs ~7-12) to hide the
// global/LDS latency the compiler refuses to pipeline at source level (R3/R4 evidence).
// MFMA passes split 2-way on output columns: LDS B-fragment traffic unchanged.
// q: ONE merged 256-row pass; Blds reused as transpose buffer after its last read.
// ksum (waves 4-7) runs concurrently with kv-MFMA (waves 0-3).
__global__ __launch_bounds__(512, 4) void k_gnqkv(
        const float* __restrict__ x,
        const float* __restrict__ sc_tab, const float* __restrict__ sh_tab,
        const short* __restrict__ wq_bf, const float* __restrict__ b_qkv,
        short* __restrict__ q_t, short* __restrict__ kvp_bf, float* __restrict__ ksp) {
    int b = blockIdx.y, nt = blockIdx.x;
    int n0 = nt * 64;
    __shared__ short Blds[64 * 264];          // [n][c^swz]; later reused as q^T [n][256]
    __shared__ short kst[64 * 72];
    __shared__ short vst[64 * 72];
    int t = threadIdx.x, lane = t & 63, wv = t >> 6, lr = lane & 15, quad = lane >> 4;

    // ---- build B tile with GN (512 thr: 8 channel-rows each) ----
    {
        const float* xb = x + (size_t)b * CH * NSP + n0;
        const float* scb = sc_tab + b * 256;
        const float* shb = sh_tab + b * 256;
        int m = t & 15, cq = t >> 4;          // cq 0..31
        #pragma unroll 2
        for (int cb = 0; cb < 8; cb++) {
            int c = cb * 32 + cq;
            float sc = scb[c], sh = shb[c];
            float4 v = *(const float4*)(xb + (size_t)c * NSP + m * 4);
            float va[4] = {v.x, v.y, v.z, v.w};
            #pragma unroll
            for (int j = 0; j < 4; j++) {
                int n = m * 4 + j;
                int cc = c ^ (((n >> 4) & 3) << 3);
                Blds[n * 264 + cc] = f2bf(va[j] * sc + sh);
            }
        }
    }
    __syncthreads();

    // ---- per-head k/v + kv/ksum partials ----
    // wave w: row-block (w&3)*32 of the 128 (k|v) rows; col-half nih=(w>>2)*2.
    // waves 0,1,4,5 compute k rows; 2,3,6,7 compute v rows.
    #pragma unroll 1
    for (int h = 0; h < 4; h++) {
        int rb = (wv & 3) * 32;                     // 0,32,64,96
        bool is_k = rb < 64;
        int gbase = (is_k ? 256 : 512) + h * 64;    // global weight-row base
        int lrow0 = is_k ? rb : rb - 64;            // 0 or 32 within the 64 rows
        int nih = (wv >> 2) * 2;                    // ni in {nih, nih+1}
        f32x4 acc[2][2] = {};
        #pragma unroll
        for (int kk = 0; kk < 8; kk++) {
            bf16x8 a0 = *(const bf16x8*)(wq_bf + (size_t)(gbase + lrow0 + lr) * 256 + kk * 32 + quad * 8);
            bf16x8 a1 = *(const bf16x8*)(wq_bf + (size_t)(gbase + lrow0 + 16 + lr) * 256 + kk * 32 + quad * 8);
            bf16x8 bfr[2];
            #pragma unroll
            for (int nj = 0; nj < 2; nj++) {
                int rr = (nih + nj) * 16 + lr;
                bfr[nj] = *(const bf16x8*)(Blds + rr * 264 + ((kk * 32 + quad * 8) ^ (((rr >> 4) & 3) << 3)));
            }
            #pragma unroll
            for (int nj = 0; nj < 2; nj++) {
                acc[0][nj] = __builtin_amdgcn_mfma_f32_16x16x32_bf16(a0, bfr[nj], acc[0][nj], 0, 0, 0);
                acc[1][nj] = __builtin_amdgcn_mfma_f32_16x16x32_bf16(a1, bfr[nj], acc[1][nj], 0, 0, 0);
            }
        }
        __syncthreads();   // prev head's kst/vst reads complete -> safe to overwrite
        short* dst = is_k ? kst : vst;
        #pragma unroll
        for (int mi = 0; mi < 2; mi++)
          #pragma unroll
          for (int nj = 0; nj < 2; nj++)
            #pragma unroll
            for (int r = 0; r < 4; r++) {
                int ol = lrow0 + mi * 16 + quad * 4 + r;   // 0..63
                int nl = (nih + nj) * 16 + lr;
                float v = acc[mi][nj][r] + b_qkv[gbase + ol];
                if (is_k) v = v > 0.f ? v + 1.f : __expf(v);   // elu(k)+1
                dst[ol * 72 + nl] = f2bf(v);
            }
        __syncthreads();
        if (wv < 4) {
            // kv^T partial: A = vst (e rows), B = kst (d rows), K = 64 n
            f32x4 acc2[4] = {};
            #pragma unroll
            for (int kk = 0; kk < 64; kk += 32) {
                bf16x8 af = *(const bf16x8*)(vst + (wv * 16 + lr) * 72 + kk + quad * 8);
                bf16x8 bfk[4];
                #pragma unroll
                for (int ni = 0; ni < 4; ni++)
                    bfk[ni] = *(const bf16x8*)(kst + (ni * 16 + lr) * 72 + kk + quad * 8);
                #pragma unroll
                for (int ni = 0; ni < 4; ni++)
                    acc2[ni] = __builtin_amdgcn_mfma_f32_16x16x32_bf16(af, bfk[ni], acc2[ni], 0, 0, 0);
            }
            short* kvdst = kvp_bf + ((size_t)(b * 4 + h) * 64 + nt) * 4096;
            #pragma unroll
            for (int ni = 0; ni < 4; ni++)
                #pragma unroll
                for (int r = 0; r < 4; r++)
                    kvdst[(wv * 16 + quad * 4 + r) * 64 + ni * 16 + lr] = f2bf(acc2[ni][r]);
        } else {
            // ksum partial (concurrent with kv on the other 4 waves)
            int tt = t - 256;                       // 0..255
            int d = tt >> 2, nq = (tt & 3) * 16;
            float s = 0.f;
            #pragma unroll
            for (int j = 0; j < 16; j++) s += bf2f(kst[d * 72 + nq + j]);
            s += __shfl_down(s, 2);
            s += __shfl_down(s, 1);
            if ((tt & 3) == 0) ksp[((size_t)(b * 4 + h) * 64 + nt) * 64 + d] = s;
        }
    }

    // ---- q: ONE merged 256-row pass; transpose staged through Blds (its last use) ----
    {
        int r0 = (wv & 3) * 64, nih = (wv >> 2) * 2;
        f32x4 acc[4][2] = {};
        #pragma unroll
        for (int kk = 0; kk < 8; kk++) {
            bf16x8 A[4];
            #pragma unroll
            for (int mi = 0; mi < 4; mi++)
                A[mi] = *(const bf16x8*)(wq_bf + (size_t)(r0 + mi * 16 + lr) * 256 + kk * 32 + quad * 8);
            bf16x8 bfr[2];
            #pragma unroll
            for (int nj = 0; nj < 2; nj++) {
                int rr = (nih + nj) * 16 + lr;
                bfr[nj] = *(const bf16x8*)(Blds + rr * 264 + ((kk * 32 + quad * 8) ^ (((rr >> 4) & 3) << 3)));
            }
            #pragma unroll
            for (int mi = 0; mi < 4; mi++)
                #pragma unroll
                for (int nj = 0; nj < 2; nj++)
                    acc[mi][nj] = __builtin_amdgcn_mfma_f32_16x16x32_bf16(A[mi], bfr[nj], acc[mi][nj], 0, 0, 0);
        }
        __syncthreads();   // all Blds reads done -> reuse as q^T buffer
        #pragma unroll
        for (int mi = 0; mi < 4; mi++)
          #pragma unroll
          for (int nj = 0; nj < 2; nj++)
            #pragma unroll
            for (int r = 0; r < 4; r++) {
                int ol = r0 + mi * 16 + quad * 4 + r;    // 0..255 (q out-channel)
                int nl = (nih + nj) * 16 + lr;           // 0..63  (n)
                float v = acc[mi][nj][r] + b_qkv[ol];
                v = v > 0.f ? v + 1.f : __expf(v);       // elu(q)+1
                Blds[nl * 264 + ol] = f2bf(v);
            }
        __syncthreads();
        #pragma unroll
        for (int i = 0; i < 4; i++) {
            int ch = t + i * 512;                  // 0..2047
            int row = ch >> 5;                     // n 0..63
            int o8 = (ch & 31) * 8;                // 0..248
            int hh = o8 >> 6, d0 = o8 & 63;
            *(u32x4*)(q_t + ((size_t)(b * 4 + hh) * NSP + n0 + row) * HD + d0) =
                *(const u32x4*)(Blds + row * 264 + o8);
        }
    }
}

// ---------------- reduce bf16 kv partials -> bf16 kvT; fp32 ksum ----------------
__global__ __launch_bounds__(256) void k_kv_reduce(
        const short* __restrict__ kvp_bf, const float* __restrict__ ksp,
        short* __restrict__ kvT_bf, float* __restrict__ ksum_g) {
    int p = blockIdx.x, bh = blockIdx.y;
    int t = threadIdx.x, lane = t & 63, grp = t >> 6;
    int chunk = p * 64 + lane;                 // 0..511, 8 elems each
    const short* base = kvp_bf + (size_t)bh * 64 * 4096 + chunk * 8;
    float s[8] = {};
    for (int ntc = grp * 16; ntc < grp * 16 + 16; ntc++) {
        bf16x8 v = *(const bf16x8*)(base + (size_t)ntc * 4096);
        #pragma unroll
        for (int j = 0; j < 8; j++) s[j] += bf2f(v[j]);
    }
    __shared__ float red[4][64][8];
    if (grp) {
        #pragma unroll
        for (int j = 0; j < 8; j++) red[grp][lane][j] = s[j];
    }
    __syncthreads();
    if (grp == 0) {
        bf16x8 rv;
        #pragma unroll
        for (int j = 0; j < 8; j++) {
            float v = s[j] + red[1][lane][j] + red[2][lane][j] + red[3][lane][j];
            rv[j] = f2bf(v);
        }
        *(bf16x8*)(kvT_bf + (size_t)bh * 4096 + chunk * 8) = rv;
    }
    if (p == 0) {   // block-uniform branch
        const float* kb = ksp + (size_t)bh * 64 * 64 + lane;
        float ss = 0.f;
        for (int ntc = grp * 16; ntc < grp * 16 + 16; ntc++) ss += kb[(size_t)ntc * 64];
        __syncthreads();
        red[grp][lane][0] = ss;
        __syncthreads();
        if (grp == 0) ksum_g[bh * 64 + lane] = ss + red[1][lane][0] + red[2][lane][0] + red[3][lane][0];
    }
}

// ---------------- fused attention + out-projection + residual ----------------
// 512 threads / 8 waves, same per-block work. 2 barriers per head. Denominator
// computed by all 512 threads (8-way d-split). Out GEMM: one merged 256-row pass.
__global__ __launch_bounds__(512, 4) void k_attn_out(
        const short* __restrict__ q_t, const short* __restrict__ kvT_bf,
        const float* __restrict__ ksum_g, const short* __restrict__ wo_bf,
        const float* __restrict__ b_out, const float* __restrict__ x,
        float* __restrict__ out) {
    int b = blockIdx.y, nt = blockIdx.x;
    int n0 = nt * 64;
    __shared__ short Battn[64 * 264];
    __shared__ short ql[64 * 72];
    __shared__ short kvl[64 * 72];
    __shared__ float dnp[8][64];
    int t = threadIdx.x, lane = t & 63, wv = t >> 6, lr = lane & 15, quad = lane >> 4;

    #pragma unroll 1
    for (int h = 0; h < 4; h++) {
        int bh = b * 4 + h;
        {   // stage ql/kvl: 512 chunks of 16B each
            int row = t >> 3, dc = (t & 7) * 8;
            *(u32x4*)(ql + row * 72 + dc) =
                *(const u32x4*)(q_t + ((size_t)bh * NSP + n0 + row) * HD + dc);
            *(u32x4*)(kvl + row * 72 + dc) =
                *(const u32x4*)(kvT_bf + (size_t)bh * 4096 + row * 64 + dc);
        }
        __syncthreads();
        {   // denom partial: thread (n = t&63, d-chunk = wv*8)
            int n = t & 63;
            bf16x8 qv = *(const bf16x8*)(ql + n * 72 + wv * 8);
            const float* ks = ksum_g + bh * 64 + wv * 8;
            float s = 0.f;
            #pragma unroll
            for (int u = 0; u < 8; u++) s += bf2f(qv[u]) * ks[u];
            dnp[wv][n] = s;
        }
        // attn MFMA: wave w -> n-rows (w&3)*16, e-col-half (w>>2)*32
        int nr = (wv & 3) * 16, nih = (wv >> 2) * 2;
        f32x4 acc[2] = {};
        #pragma unroll
        for (int kk = 0; kk < 64; kk += 32) {
            bf16x8 af = *(const bf16x8*)(ql + (nr + lr) * 72 + kk + quad * 8);
            #pragma unroll
            for (int nj = 0; nj < 2; nj++) {
                bf16x8 bfr = *(const bf16x8*)(kvl + ((nih + nj) * 16 + lr) * 72 + kk + quad * 8);
                acc[nj] = __builtin_amdgcn_mfma_f32_16x16x32_bf16(af, bfr, acc[nj], 0, 0, 0);
            }
        }
        __syncthreads();   // dnp complete; ql/kvl reads complete
        float dn[4];
        #pragma unroll
        for (int r = 0; r < 4; r++) {
            int n = nr + quad * 4 + r;
            float s = dnp[0][n] + dnp[1][n] + dnp[2][n] + dnp[3][n]
                    + dnp[4][n] + dnp[5][n] + dnp[6][n] + dnp[7][n];
            dn[r] = 1.f / (s + 1e-6f);
        }
        #pragma unroll
        for (int nj = 0; nj < 2; nj++)
            #pragma unroll
            for (int r = 0; r < 4; r++) {
                int n = nr + quad * 4 + r;
                Battn[n * 264 + h * 64 + (nih + nj) * 16 + lr] = f2bf(acc[nj][r] * dn[r]);
            }
        // no barrier: next stage writes ql/kvl (disjoint from Battn); dnp overwrite
        // is gated by the post-stage barrier, which all waves reach only after their
        // Battn writes retire.
    }
    __syncthreads();

    // out GEMM: one merged pass; wave w -> o-rows (w&3)*64 + mi*16, col-half (w>>2)*32
    {
        int r0 = (wv & 3) * 64, nih = (wv >> 2) * 2;
        f32x4 acc[4][2] = {};
        #pragma unroll
        for (int kk = 0; kk < 8; kk++) {
            bf16x8 A[4];
            #pragma unroll
            for (int mi = 0; mi < 4; mi++)
                A[mi] = *(const bf16x8*)(wo_bf + (size_t)(r0 + mi * 16 + lr) * 256 + kk * 32 + quad * 8);
            bf16x8 bfr[2];
            #pragma unroll
            for (int nj = 0; nj < 2; nj++)
                bfr[nj] = *(const bf16x8*)(Battn + ((nih + nj) * 16 + lr) * 264 + kk * 32 + quad * 8);
            #pragma unroll
            for (int mi = 0; mi < 4; mi++)
                #pragma unroll
                for (int nj = 0; nj < 2; nj++)
                    acc[mi][nj] = __builtin_amdgcn_mfma_f32_16x16x32_bf16(A[mi], bfr[nj], acc[mi][nj], 0, 0, 0);
        }
        #pragma unroll
        for (int mi = 0; mi < 4; mi++)
          #pragma unroll
          for (int nj = 0; nj < 2; nj++)
            #pragma unroll
            for (int r = 0; r < 4; r++) {
                int o = r0 + mi * 16 + quad * 4 + r;
                int nl = (nih + nj) * 16 + lr;
                size_t idx = ((size_t)b * CH + o) * NSP + n0 + nl;
                out[idx] = acc[mi][nj][r] + b_out[o] + x[idx];
            }
    }
}

extern "C" void kernel_launch(void* const* d_in, const int* in_sizes, int n_in,
                              void* d_out, int out_size, void* d_ws, size_t ws_size,
                              hipStream_t stream) {
    const float* x     = (const float*)d_in[0];
    const float* gamma = (const float*)d_in[1];
    const float* beta  = (const float*)d_in[2];
    const float* w_qkv = (const float*)d_in[3];
    const float* b_qkv = (const float*)d_in[4];
    const float* w_out = (const float*)d_in[5];
    const float* b_out = (const float*)d_in[6];
    float* out = (float*)d_out;

    char* ws = (char*)d_ws;
    size_t off = 0;
    float* sc_tab = (float*)(ws + off); off += (size_t)16 * 256 * 4;
    float* sh_tab = (float*)(ws + off); off += (size_t)16 * 256 * 4;
    short* wq_bf  = (short*)(ws + off); off += (size_t)768 * 256 * 2;
    short* wo_bf  = (short*)(ws + off); off += (size_t)256 * 256 * 2;
    short* q_t    = (short*)(ws + off); off += (size_t)BATCH * NSP * CH * 2;   // [b][h][n][d]
    short* kvp_bf = (short*)(ws + off); off += (size_t)64 * 64 * 4096 * 2;     // [bh][nt64][e][d] bf16
    float* ksp    = (float*)(ws + off); off += (size_t)64 * 64 * 64 * 4;       // [bh][nt64][d]
    short* kvT_bf = (short*)(ws + off); off += (size_t)64 * 4096 * 2;          // [bh][e][d] bf16
    float* ksum_g = (float*)(ws + off); off += (size_t)64 * 64 * 4;            // [bh][d]

    if (ws_size < off) return;

    k_pre<<<768, 256, 0, stream>>>(x, w_qkv, w_out, gamma, beta, sc_tab, sh_tab, wq_bf, wo_bf);
    k_gnqkv<<<dim3(64, 16), 512, 0, stream>>>(x, sc_tab, sh_tab, wq_bf, b_qkv, q_t, kvp_bf, ksp);
    k_kv_reduce<<<dim3(8, 64), 256, 0, stream>>>(kvp_bf, ksp, kvT_bf, ksum_g);
    k_attn_out<<<dim3(64, 16), 512, 0, stream>>>(q_t, kvT_bf, ksum_g, wo_bf, b_out, x, out);
}

// Round 6
// 259.274 us; speedup vs baseline: 1.1310x; 1.1310x over previous
//
#include <hip/hip_runtime.h>
#include <hip/hip_bf16.h>
#include <stdint.h>

#define BATCH 16
#define CH    256
#define NSP   4096   // 64*64 spatial
#define NH    4
#define HD    64

typedef __attribute__((ext_vector_type(8))) short bf16x8;
typedef __attribute__((ext_vector_type(4))) float f32x4;
typedef __attribute__((ext_vector_type(4))) unsigned int u32x4;

// hardware RNE bf16 convert (compiler emits v_cvt_pk_bf16_f32; 1 op vs 4-op bit hack)
__device__ __forceinline__ short f2bf(float f) {
    __hip_bfloat16 h = __float2bfloat16(f);
    union { __hip_bfloat16 h; short s; } u; u.h = h;
    return u.s;
}
__device__ __forceinline__ float bf2f(short s) {
    union { float f; unsigned u; } v; v.u = ((unsigned)(unsigned short)s) << 16;
    return v.f;
}

// ---------------- fused: GN stats (blocks 0..511) + weight bf16 convert (512..767) ----------------
__global__ __launch_bounds__(256) void k_pre(
        const float* __restrict__ x, const float* __restrict__ wq, const float* __restrict__ wo,
        float* __restrict__ mu, float* __restrict__ rstd,
        short* __restrict__ wq_bf, short* __restrict__ wo_bf) {
    int bg = blockIdx.x;
    if (bg < 512) {
        const float4* p = (const float4*)(x + (size_t)bg * 32768);
        float s = 0.f, sq = 0.f;
        for (int i = threadIdx.x; i < 8192; i += 256) {
            float4 v = p[i];
            s  += v.x + v.y + v.z + v.w;
            sq += v.x * v.x + v.y * v.y + v.z * v.z + v.w * v.w;
        }
        for (int off = 32; off; off >>= 1) { s += __shfl_down(s, off); sq += __shfl_down(sq, off); }
        __shared__ float ls[4], lq[4];
        int w = threadIdx.x >> 6;
        if ((threadIdx.x & 63) == 0) { ls[w] = s; lq[w] = sq; }
        __syncthreads();
        if (threadIdx.x == 0) {
            float S = ls[0] + ls[1] + ls[2] + ls[3];
            float Q = lq[0] + lq[1] + lq[2] + lq[3];
            float m = S / 32768.f;
            float var = Q / 32768.f - m * m;
            mu[bg] = m; rstd[bg] = rsqrtf(var + 1e-5f);
        }
    } else {
        int idx = ((bg - 512) * 256 + threadIdx.x) * 4;
        float4 v;
        short* dst;
        if (idx < 196608) { v = *(const float4*)(wq + idx); dst = wq_bf + idx; }
        else              { v = *(const float4*)(wo + (idx - 196608)); dst = wo_bf + (idx - 196608); }
        unsigned p0 = ((unsigned)(unsigned short)f2bf(v.x)) | (((unsigned)(unsigned short)f2bf(v.y)) << 16);
        unsigned p1 = ((unsigned)(unsigned short)f2bf(v.z)) | (((unsigned)(unsigned short)f2bf(v.w)) << 16);
        uint2 pk; pk.x = p0; pk.y = p1;
        *(uint2*)dst = pk;
    }
}

// ---------------- fused GN-apply + QKV + kv^T/ksum partials + q_t ----------------
// EXACT R0 structure (proven 90us): grid (64,16), 256 thr, barrier-free K-loops with
// A direct from L2. Only delta vs R0: f2bf is the 1-op hardware convert.
__global__ __launch_bounds__(256) void k_gnqkv(
        const float* __restrict__ x, const float* __restrict__ gamma, const float* __restrict__ beta,
        const float* __restrict__ mu, const float* __restrict__ rstd,
        const short* __restrict__ wq_bf, const float* __restrict__ b_qkv,
        short* __restrict__ q_t, short* __restrict__ kvp_bf, float* __restrict__ ksp) {
    int b = blockIdx.y, nt = blockIdx.x;
    int n0 = nt * 64;
    __shared__ short Blds[64 * 264];          // [n][c^swz]
    __shared__ union UR {
        struct { short kst[64 * 72]; short vst[64 * 72]; } s;
        short cst[64 * 136];
    } R;
    int t = threadIdx.x, lane = t & 63, wv = t >> 6, lr = lane & 15, quad = lane >> 4;

    // ---- build B tile with GN ----
    {
        const float* xb = x + (size_t)b * CH * NSP;
        int m = t & 15, cq = t >> 4;
        for (int cb = 0; cb < 16; cb++) {
            int c = cb * 16 + cq;
            int g = c >> 3;
            float sc = rstd[b * 32 + g] * gamma[c];
            float sh = beta[c] - mu[b * 32 + g] * sc;
            float4 v = *(const float4*)(xb + (size_t)c * NSP + n0 + m * 4);
            float vv[4] = {v.x, v.y, v.z, v.w};
            #pragma unroll
            for (int j = 0; j < 4; j++) {
                int n = m * 4 + j;
                int cc = c ^ (((n >> 4) & 3) << 3);
                Blds[n * 264 + cc] = f2bf(vv[j] * sc + sh);
            }
        }
    }
    __syncthreads();

    // ---- per-head k/v + kv partial ----
    for (int h = 0; h < 4; h++) {
        int base_row = (wv < 2 ? 256 : 512) + h * 64;   // k rows for waves 0-1, v rows for 2-3
        int sub = (wv & 1) * 32;
        f32x4 acc[2][4] = {};
        for (int k0 = 0; k0 < 256; k0 += 32) {          // barrier-free K-loop
            bf16x8 afr[2], bfr[4];
            #pragma unroll
            for (int mi = 0; mi < 2; mi++)
                afr[mi] = *(const bf16x8*)(wq_bf + (size_t)(base_row + sub + mi * 16 + lr) * 256 + k0 + quad * 8);
            #pragma unroll
            for (int ni = 0; ni < 4; ni++) {
                int rr = ni * 16 + lr;
                bfr[ni] = *(const bf16x8*)(Blds + rr * 264 + ((k0 + quad * 8) ^ (((rr >> 4) & 3) << 3)));
            }
            #pragma unroll
            for (int mi = 0; mi < 2; mi++)
                #pragma unroll
                for (int ni = 0; ni < 4; ni++)
                    acc[mi][ni] = __builtin_amdgcn_mfma_f32_16x16x32_bf16(afr[mi], bfr[ni], acc[mi][ni], 0, 0, 0);
        }
        __syncthreads();   // protect R reuse from previous pass
        short* dst = (wv < 2) ? R.s.kst : R.s.vst;
        bool is_k = (wv < 2);
        #pragma unroll
        for (int mi = 0; mi < 2; mi++)
          #pragma unroll
          for (int ni = 0; ni < 4; ni++)
            #pragma unroll
            for (int r = 0; r < 4; r++) {
                int ol = sub + mi * 16 + quad * 4 + r;   // 0..63
                int nl = ni * 16 + lr;
                float v = acc[mi][ni][r] + b_qkv[base_row + ol];
                if (is_k) v = v > 0.f ? v + 1.f : __expf(v);   // elu(k)+1
                dst[ol * 72 + nl] = f2bf(v);
            }
        __syncthreads();
        // ksum partial
        {
            int d = t >> 2, nq = (t & 3) * 16;
            float s = 0.f;
            #pragma unroll
            for (int j = 0; j < 16; j++) s += bf2f(R.s.kst[d * 72 + nq + j]);
            s += __shfl_down(s, 2);
            s += __shfl_down(s, 1);
            if ((t & 3) == 0) ksp[((size_t)(b * 4 + h) * 64 + nt) * 64 + d] = s;
        }
        // kv^T partial: A = vst (e rows), B = kst (d rows), K = 64 n
        f32x4 acc2[4] = {};
        #pragma unroll
        for (int kk = 0; kk < 64; kk += 32) {
            bf16x8 af = *(const bf16x8*)(R.s.vst + (wv * 16 + lr) * 72 + kk + quad * 8);
            bf16x8 bfk[4];
            #pragma unroll
            for (int ni = 0; ni < 4; ni++)
                bfk[ni] = *(const bf16x8*)(R.s.kst + (ni * 16 + lr) * 72 + kk + quad * 8);
            #pragma unroll
            for (int ni = 0; ni < 4; ni++)
                acc2[ni] = __builtin_amdgcn_mfma_f32_16x16x32_bf16(af, bfk[ni], acc2[ni], 0, 0, 0);
        }
        short* kvdst = kvp_bf + ((size_t)(b * 4 + h) * 64 + nt) * 4096;
        #pragma unroll
        for (int ni = 0; ni < 4; ni++)
            #pragma unroll
            for (int r = 0; r < 4; r++)
                kvdst[(wv * 16 + quad * 4 + r) * 64 + ni * 16 + lr] = f2bf(acc2[ni][r]);
    }

    // ---- q passes (128 rows each), barrier-free K-loop ----
    for (int mtq = 0; mtq < 2; mtq++) {
        f32x4 acc[2][4] = {};
        int wm = wv * 32;
        for (int k0 = 0; k0 < 256; k0 += 32) {
            bf16x8 afr[2], bfr[4];
            #pragma unroll
            for (int mi = 0; mi < 2; mi++)
                afr[mi] = *(const bf16x8*)(wq_bf + (size_t)(mtq * 128 + wm + mi * 16 + lr) * 256 + k0 + quad * 8);
            #pragma unroll
            for (int ni = 0; ni < 4; ni++) {
                int rr = ni * 16 + lr;
                bfr[ni] = *(const bf16x8*)(Blds + rr * 264 + ((k0 + quad * 8) ^ (((rr >> 4) & 3) << 3)));
            }
            #pragma unroll
            for (int mi = 0; mi < 2; mi++)
                #pragma unroll
                for (int ni = 0; ni < 4; ni++)
                    acc[mi][ni] = __builtin_amdgcn_mfma_f32_16x16x32_bf16(afr[mi], bfr[ni], acc[mi][ni], 0, 0, 0);
        }
        __syncthreads();   // protect cst reuse
        #pragma unroll
        for (int mi = 0; mi < 2; mi++)
          #pragma unroll
          for (int ni = 0; ni < 4; ni++)
            #pragma unroll
            for (int r = 0; r < 4; r++) {
                int ol = wm + mi * 16 + quad * 4 + r;    // 0..127
                int nl = ni * 16 + lr;
                float v = acc[mi][ni][r] + b_qkv[mtq * 128 + ol];
                v = v > 0.f ? v + 1.f : __expf(v);       // elu(q)+1
                R.cst[nl * 136 + ol] = f2bf(v);
            }
        __syncthreads();
        #pragma unroll
        for (int i = 0; i < 4; i++) {
            int ch = t + i * 256;
            int row = ch >> 4, o8 = (ch & 15) * 8;
            int hh = mtq * 2 + (o8 >> 6), d0 = o8 & 63;
            *(u32x4*)(q_t + ((size_t)(b * 4 + hh) * NSP + n0 + row) * HD + d0) =
                *(const u32x4*)(R.cst + row * 136 + o8);
        }
    }
}

// ---------------- reduce bf16 kv partials -> bf16 kvT; fp32 ksum ----------------
// 512 blocks; 4 wave-groups each reduce 16 of the 64 n-tile partials, LDS combine.
__global__ __launch_bounds__(256) void k_kv_reduce(
        const short* __restrict__ kvp_bf, const float* __restrict__ ksp,
        short* __restrict__ kvT_bf, float* __restrict__ ksum_g) {
    int p = blockIdx.x, bh = blockIdx.y;
    int t = threadIdx.x, lane = t & 63, grp = t >> 6;
    int chunk = p * 64 + lane;                 // 0..511, 8 elems each
    const short* base = kvp_bf + (size_t)bh * 64 * 4096 + chunk * 8;
    float s[8] = {};
    for (int ntc = grp * 16; ntc < grp * 16 + 16; ntc++) {
        bf16x8 v = *(const bf16x8*)(base + (size_t)ntc * 4096);
        #pragma unroll
        for (int j = 0; j < 8; j++) s[j] += bf2f(v[j]);
    }
    __shared__ float red[4][64][8];
    if (grp) {
        #pragma unroll
        for (int j = 0; j < 8; j++) red[grp][lane][j] = s[j];
    }
    __syncthreads();
    if (grp == 0) {
        bf16x8 rv;
        #pragma unroll
        for (int j = 0; j < 8; j++) {
            float v = s[j] + red[1][lane][j] + red[2][lane][j] + red[3][lane][j];
            rv[j] = f2bf(v);
        }
        *(bf16x8*)(kvT_bf + (size_t)bh * 4096 + chunk * 8) = rv;
    }
    if (p == 0) {   // block-uniform branch
        const float* kb = ksp + (size_t)bh * 64 * 64 + lane;
        float ss = 0.f;
        for (int ntc = grp * 16; ntc < grp * 16 + 16; ntc++) ss += kb[(size_t)ntc * 64];
        __syncthreads();
        red[grp][lane][0] = ss;
        __syncthreads();
        if (grp == 0) ksum_g[bh * 64 + lane] = ss + red[1][lane][0] + red[2][lane][0] + red[3][lane][0];
    }
}

// ---------------- fused attention + PER-HEAD out-projection + residual ----------------
// Key change: out-GEMM accumulated per head (acc_out += Wout[:,h*64:]@Battn_h), so the
// full [64n][256e] Battn shrinks to a per-head [64][64] slice. LDS 52.7KB -> 27.1KB and
// launch_bounds(256,4) (VGPR<=128) -> 4 blocks/CU resident: 1024 blocks = exactly ONE
// round (R0-R5 evidence: total time = rounds x block latency; tail round was ~33%).
__global__ __launch_bounds__(256, 4) void k_attn_out(
        const short* __restrict__ q_t, const short* __restrict__ kvT_bf,
        const float* __restrict__ ksum_g, const short* __restrict__ wo_bf,
        const float* __restrict__ b_out, const float* __restrict__ x,
        float* __restrict__ out) {
    int b = blockIdx.y, nt = blockIdx.x;
    int n0 = nt * 64;
    __shared__ short ql[64 * 68];    // [n][d]
    __shared__ short kvl[64 * 68];   // [e][d]
    __shared__ short Bh[64 * 68];    // [n][e] this head's normalized attn output
    __shared__ float dnp[4][64];
    int t = threadIdx.x, lane = t & 63, wv = t >> 6, lr = lane & 15, quad = lane >> 4;

    f32x4 aco[4][4] = {};            // out rows wv*64+mi*16, cols nj*16 (held across heads)
    int r0 = wv * 64;

    #pragma unroll 1
    for (int h = 0; h < 4; h++) {
        int bh = b * 4 + h;
        #pragma unroll
        for (int i = 0; i < 2; i++) {
            int ch = t + i * 256;
            int row = ch >> 3, dc = (ch & 7) * 8;
            *(u32x4*)(ql + row * 68 + dc) =
                *(const u32x4*)(q_t + ((size_t)bh * NSP + n0 + row) * HD + dc);
            *(u32x4*)(kvl + row * 68 + dc) =
                *(const u32x4*)(kvT_bf + (size_t)bh * 4096 + row * 64 + dc);
        }
        __syncthreads();
        {   // denom partial: thread (n=t&63, d-range=wv*16), fully parallel
            int n = t & 63, q0 = wv * 16;
            const float* ks = ksum_g + bh * 64 + q0;
            float s = 0.f;
            #pragma unroll
            for (int j = 0; j < 16; j += 8) {
                bf16x8 qv = *(const bf16x8*)(ql + n * 68 + q0 + j);
                #pragma unroll
                for (int u = 0; u < 8; u++) s += bf2f(qv[u]) * ks[j + u];
            }
            dnp[wv][n] = s;
        }
        // attn MFMA: wave -> n rows wv*16, all 64 e
        f32x4 acc2[4] = {};
        int nr = wv * 16;
        #pragma unroll
        for (int kk = 0; kk < 64; kk += 32) {
            bf16x8 af = *(const bf16x8*)(ql + (nr + lr) * 68 + kk + quad * 8);
            bf16x8 bfr[4];
            #pragma unroll
            for (int ni = 0; ni < 4; ni++)
                bfr[ni] = *(const bf16x8*)(kvl + (ni * 16 + lr) * 68 + kk + quad * 8);
            #pragma unroll
            for (int ni = 0; ni < 4; ni++)
                acc2[ni] = __builtin_amdgcn_mfma_f32_16x16x32_bf16(af, bfr[ni], acc2[ni], 0, 0, 0);
        }
        __syncthreads();      // dnp complete; ql/kvl reads complete
        float dn[4];
        #pragma unroll
        for (int r = 0; r < 4; r++) {
            int n = nr + quad * 4 + r;
            dn[r] = 1.f / (dnp[0][n] + dnp[1][n] + dnp[2][n] + dnp[3][n] + 1e-6f);
        }
        #pragma unroll
        for (int ni = 0; ni < 4; ni++)
            #pragma unroll
            for (int r = 0; r < 4; r++) {
                int n = nr + quad * 4 + r;
                Bh[n * 68 + ni * 16 + lr] = f2bf(acc2[ni][r] * dn[r]);
            }
        __syncthreads();      // Bh ready for all waves
        // out-GEMM partial over this head's 64-wide e slice (A from L2, barrier-free)
        #pragma unroll
        for (int kk = 0; kk < 2; kk++) {
            bf16x8 A[4];
            #pragma unroll
            for (int mi = 0; mi < 4; mi++)
                A[mi] = *(const bf16x8*)(wo_bf + (size_t)(r0 + mi * 16 + lr) * 256 + h * 64 + kk * 32 + quad * 8);
            bf16x8 bfr[4];
            #pragma unroll
            for (int nj = 0; nj < 4; nj++)
                bfr[nj] = *(const bf16x8*)(Bh + (nj * 16 + lr) * 68 + kk * 32 + quad * 8);
            #pragma unroll
            for (int mi = 0; mi < 4; mi++)
                #pragma unroll
                for (int nj = 0; nj < 4; nj++)
                    aco[mi][nj] = __builtin_amdgcn_mfma_f32_16x16x32_bf16(A[mi], bfr[nj], aco[mi][nj], 0, 0, 0);
        }
        // no barrier: next stage writes ql/kvl (disjoint from Bh); Bh's next
        // overwrite is two barriers away, by which point these reads are drained.
    }

    #pragma unroll
    for (int mi = 0; mi < 4; mi++)
      #pragma unroll
      for (int nj = 0; nj < 4; nj++)
        #pragma unroll
        for (int r = 0; r < 4; r++) {
            int o = r0 + mi * 16 + quad * 4 + r;
            int nl = nj * 16 + lr;
            size_t idx = ((size_t)b * CH + o) * NSP + n0 + nl;
            out[idx] = aco[mi][nj][r] + b_out[o] + x[idx];
        }
}

extern "C" void kernel_launch(void* const* d_in, const int* in_sizes, int n_in,
                              void* d_out, int out_size, void* d_ws, size_t ws_size,
                              hipStream_t stream) {
    const float* x     = (const float*)d_in[0];
    const float* gamma = (const float*)d_in[1];
    const float* beta  = (const float*)d_in[2];
    const float* w_qkv = (const float*)d_in[3];
    const float* b_qkv = (const float*)d_in[4];
    const float* w_out = (const float*)d_in[5];
    const float* b_out = (const float*)d_in[6];
    float* out = (float*)d_out;

    char* ws = (char*)d_ws;
    size_t off = 0;
    float* mu     = (float*)(ws + off); off += 2048;
    float* rstd   = (float*)(ws + off); off += 2048;
    short* wq_bf  = (short*)(ws + off); off += (size_t)768 * 256 * 2;
    short* wo_bf  = (short*)(ws + off); off += (size_t)256 * 256 * 2;
    short* q_t    = (short*)(ws + off); off += (size_t)BATCH * NSP * CH * 2;   // [b][h][n][d]
    short* kvp_bf = (short*)(ws + off); off += (size_t)64 * 64 * 4096 * 2;     // [bh][nt64][e][d] bf16
    float* ksp    = (float*)(ws + off); off += (size_t)64 * 64 * 64 * 4;       // [bh][nt64][d]
    short* kvT_bf = (short*)(ws + off); off += (size_t)64 * 4096 * 2;          // [bh][e][d] bf16
    float* ksum_g = (float*)(ws + off); off += (size_t)64 * 64 * 4;            // [bh][d]

    if (ws_size < off) return;

    k_pre<<<768, 256, 0, stream>>>(x, w_qkv, w_out, mu, rstd, wq_bf, wo_bf);
    k_gnqkv<<<dim3(64, 16), 256, 0, stream>>>(x, gamma, beta, mu, rstd, wq_bf, b_qkv, q_t, kvp_bf, ksp);
    k_kv_reduce<<<dim3(8, 64), 256, 0, stream>>>(kvp_bf, ksp, kvT_bf, ksum_g);
    k_attn_out<<<dim3(64, 16), 256, 0, stream>>>(q_t, kvT_bf, ksum_g, wo_bf, b_out, x, out);
}